// Round 1
// baseline (183.049 us; speedup 1.0000x reference)
//
#include <hip/hip_runtime.h>

// Reference collapse (see analysis):
//   A[b,n,h,l] = 1/256 exactly (softmax of a constant vector; k is all-ones)
//   V[b, n*16+h, d] = (1/256) * sum_{l=0}^{15} v[b, l*256 + n, d]   (independent of h)
// q is never needed. Pure memory-bound: read 64 MiB (v), write 96 MiB (V + A).

#define BB 8
#define LL 4096
#define DD 512
#define HH 16
#define NN 256           // LL / HH
#define D4 (DD / 4)      // 128 float4 per row

// Block layout:
//   blocks [0, 1024):    V computation, 1 thread per (b, n, d4) -> 8*256*128 = 262144 threads
//   blocks [1024, 3072): A fill, grid-strided float4 writes of 1/256

__global__ __launch_bounds__(256) void attn_collapse_kernel(
    const float4* __restrict__ v, float4* __restrict__ out)
{
    const int blk = blockIdx.x;
    if (blk < 1024) {
        const int t  = blk * 256 + threadIdx.x;   // 0 .. 262143
        const int d4 = t & (D4 - 1);              // 0 .. 127
        const int n  = (t >> 7) & (NN - 1);       // 0 .. 255
        const int b  = t >> 15;                   // 0 .. 7

        // v float4 index: (b*4096 + l*256 + n)*128 + d4, stride over l = 256*128
        const float4* vp = v + ((size_t)(b * LL + n) * D4 + d4);
        float4 acc = make_float4(0.f, 0.f, 0.f, 0.f);
#pragma unroll
        for (int l = 0; l < HH; ++l) {
            float4 x = vp[(size_t)l * NN * D4];
            acc.x += x.x; acc.y += x.y; acc.z += x.z; acc.w += x.w;
        }
        const float s = 1.0f / 256.0f;
        acc.x *= s; acc.y *= s; acc.z *= s; acc.w *= s;

        // out V float4 index: (b*4096 + n*16 + h)*128 + d4, stride over h = 128
        float4* op = out + ((size_t)(b * LL + n * HH) * D4 + d4);
#pragma unroll
        for (int h = 0; h < HH; ++h) {
            op[(size_t)h * D4] = acc;
        }
    } else {
        // A region: starts at float4 offset BB*LL*D4 = 4,194,304; spans 2,097,152 float4
        const size_t a_base  = (size_t)BB * LL * D4;
        const size_t a_count = (size_t)BB * NN * HH * NN / 4;   // 2,097,152
        const size_t nthreads = 2048u * 256u;                    // 524,288
        size_t t = (size_t)(blk - 1024) * 256 + threadIdx.x;
        const float4 val = make_float4(1.0f / 256.0f, 1.0f / 256.0f,
                                       1.0f / 256.0f, 1.0f / 256.0f);
        for (size_t i = t; i < a_count; i += nthreads) {
            out[a_base + i] = val;
        }
    }
}

extern "C" void kernel_launch(void* const* d_in, const int* in_sizes, int n_in,
                              void* d_out, int out_size, void* d_ws, size_t ws_size,
                              hipStream_t stream) {
    // d_in[0] = q (unused), d_in[1] = v
    const float4* v = (const float4*)d_in[1];
    float4* out = (float4*)d_out;
    attn_collapse_kernel<<<dim3(3072), dim3(256), 0, stream>>>(v, out);
}

// Round 3
// 177.112 us; speedup vs baseline: 1.0335x; 1.0335x over previous
//
#include <hip/hip_runtime.h>

// Reference collapse (verified absmax=0.0 in R1):
//   A[b,n,h,l] = 1/256 exactly (softmax of a constant vector; k is all-ones)
//   V[b, n*16+h, d] = (1/256) * sum_{l=0}^{15} v[b, l*256 + n, d]   (independent of h)
// q is never read. Pure memory-bound: read 64 MiB (v), write 192 MiB (V 64 + A 128).
// Roofline: 268 MB / ~6.6 TB/s ~= 41 us for this kernel.
//
// R3: same as R2 but with clang ext_vector_type for the nontemporal builtins
// (HIP float4 is a struct and is rejected by __builtin_nontemporal_*).

#define BB 8
#define LL 4096
#define DD 512
#define HH 16
#define NN 256           // LL / HH
#define D4 (DD / 4)      // 128 float4 per row

typedef float vfloat4 __attribute__((ext_vector_type(4)));

// Block layout:
//   blocks [0, 1024):    V computation, 1 thread per (b, n, d4) -> 262144 threads
//   blocks [1024, 3072): A fill, grid-strided float4 writes of 1/256 (8,388,608 float4)

__global__ __launch_bounds__(256) void attn_collapse_kernel(
    const vfloat4* __restrict__ v, vfloat4* __restrict__ out)
{
    const int blk = blockIdx.x;
    if (blk < 1024) {
        const int t  = blk * 256 + threadIdx.x;   // 0 .. 262143
        const int d4 = t & (D4 - 1);              // 0 .. 127
        const int n  = (t >> 7) & (NN - 1);       // 0 .. 255
        const int b  = t >> 15;                   // 0 .. 7

        // v float4 index: (b*4096 + l*256 + n)*128 + d4, stride over l = 256*128 f4
        const vfloat4* vp = v + ((size_t)(b * LL + n) * D4 + d4);
        vfloat4 acc = (vfloat4)(0.f, 0.f, 0.f, 0.f);
#pragma unroll
        for (int l = 0; l < HH; ++l) {
            vfloat4 x = __builtin_nontemporal_load(&vp[(size_t)l * NN * D4]);
            acc += x;
        }
        acc *= (1.0f / 256.0f);

        // out V float4 index: (b*4096 + n*16 + h)*128 + d4, stride over h = 128 f4
        vfloat4* op = out + ((size_t)(b * LL + n * HH) * D4 + d4);
#pragma unroll
        for (int h = 0; h < HH; ++h) {
            __builtin_nontemporal_store(acc, &op[(size_t)h * D4]);
        }
    } else {
        // A region: starts at float4 offset BB*LL*D4 = 4,194,304;
        // spans BB*NN*HH*NN/4 = 8,388,608 float4 (128 MiB)
        const size_t a_base  = (size_t)BB * LL * D4;
        const size_t a_count = (size_t)BB * NN * HH * NN / 4;
        const size_t nthreads = 2048u * 256u;                    // 524,288
        size_t t = (size_t)(blk - 1024) * 256 + threadIdx.x;
        const vfloat4 val = (vfloat4)(1.0f / 256.0f, 1.0f / 256.0f,
                                      1.0f / 256.0f, 1.0f / 256.0f);
        for (size_t i = t; i < a_count; i += nthreads) {
            __builtin_nontemporal_store(val, &out[a_base + i]);
        }
    }
}

extern "C" void kernel_launch(void* const* d_in, const int* in_sizes, int n_in,
                              void* d_out, int out_size, void* d_ws, size_t ws_size,
                              hipStream_t stream) {
    // d_in[0] = q (unused), d_in[1] = v
    const vfloat4* v = (const vfloat4*)d_in[1];
    vfloat4* out = (vfloat4*)d_out;
    attn_collapse_kernel<<<dim3(3072), dim3(256), 0, stream>>>(v, out);
}